// Round 6
// baseline (1494.684 us; speedup 1.0000x reference)
//
#include <hip/hip_runtime.h>

#define PN 50000
#define LN 8000
#define HN 8
#define DEGN 64
#define SSN 32

// ---- fast-but-accurate nonlinearities (error ~1e-7 rel) ----
static __device__ __forceinline__ float rcp_(float x){ return __builtin_amdgcn_rcpf(x); }
static __device__ __forceinline__ float sig_(float x){ return rcp_(1.0f + __expf(-x)); }
static __device__ __forceinline__ float tanh_(float x){ return 1.0f - 2.0f*rcp_(__expf(2.0f*x) + 1.0f); }

// ws layout (float offsets)
#define OFF_PWHP 0          // path_Wh packed [lane(64)][k16(16)][3]  3072
#define OFF_PWXP 3072       // path_Wx packed [k][j][4]            8192
#define OFF_QWXP 11264      // queue_Wx packed [k][j][4]           4096
#define OFF_QWHP 15360      // queue_Wh packed [k][j][4]           4096
#define OFF_LWXP 19456      // link_Wx packed [k][j][4]            4096
#define OFF_LWHP 23552      // link_Wh packed [k][j][4]            4096
#define OFF_PATH 27648      // path_state (P,32)                   1600000
#define OFF_SEQ  1627648    // seq (P,8,32)                        12800000
#define OFF_QST  14427648   // queue_state (L,32)                  256000
#define OFF_LST  14683648   // link_state (L,32)                   256000
#define OFF_G    14939648   // G (L,96) plane layout [{z,r,n}][j]  768000
// total 15707648 floats = 62.8 MB

// ---------------- weight packing ----------------
__global__ __launch_bounds__(256) void k_pack(
    const float* __restrict__ pWh, const float* __restrict__ pWx,
    const float* __restrict__ qWx, const float* __restrict__ qWh,
    const float* __restrict__ lWx, const float* __restrict__ lWh,
    float* __restrict__ ws)
{
    int i = blockIdx.x*256 + threadIdx.x;
    int i0 = i;
    if (i0 < 3072){ // per-lane 48-weight layout: lane=(half*32+j), [k16][gate]
        int lane=i0/48, r=i0%48, k16=r/3, g=r%3;
        int half=lane>>5, j=lane&31;
        ws[OFF_PWHP+i0] = pWh[(half*16+k16)*96 + g*32 + j]; return; }
    i0 -= 3072;
    if (i0 < 8192){ int k=i0/128, r=i0%128, j=r/4, c=r%4;
        ws[OFF_PWXP+i0] = (c<3)? pWx[k*96 + c*32 + j] : 0.f; return; }
    i0 -= 8192;
    if (i0 < 4096){ int k=i0/128, r=i0%128, j=r/4, c=r%4;
        ws[OFF_QWXP+i0] = (c<3)? qWx[k*96 + c*32 + j] : 0.f; return; }
    i0 -= 4096;
    if (i0 < 4096){ int k=i0/128, r=i0%128, j=r/4, c=r%4;
        ws[OFF_QWHP+i0] = (c<3)? qWh[k*96 + c*32 + j] : 0.f; return; }
    i0 -= 4096;
    if (i0 < 4096){ int k=i0/128, r=i0%128, j=r/4, c=r%4;
        ws[OFF_LWXP+i0] = (c<3)? lWx[k*96 + c*32 + j] : 0.f; return; }
    i0 -= 4096;
    if (i0 < 4096){ int k=i0/128, r=i0%128, j=r/4, c=r%4;
        ws[OFF_LWHP+i0] = (c<3)? lWh[k*96 + c*32 + j] : 0.f; return; }
}

// ---------------- path encoder: path_state = mlp2(feats) ----------------
__global__ __launch_bounds__(256, 4) void k_path_init(
    const float* __restrict__ ft, const float* __restrict__ fpk,
    const float* __restrict__ flam, const float* __restrict__ fob,
    const float* __restrict__ fon, const float* __restrict__ foff,
    const int* __restrict__ fdist,
    const float* __restrict__ w1, const float* __restrict__ b1,
    const float* __restrict__ w2, const float* __restrict__ b2,
    float* __restrict__ path_state)
{
    int p = blockIdx.x*256 + threadIdx.x; if (p >= PN) p = PN-1;
    float f[9];
    f[0]=ft[p]; f[1]=fpk[p];
    int dcls = fdist[p];
    f[2] = (dcls==0)?1.f:0.f; f[3]=(dcls==1)?1.f:0.f; f[4]=(dcls==2)?1.f:0.f;
    f[5]=flam[p]; f[6]=fob[p]; f[7]=fon[p]; f[8]=foff[p];
    float h1[SSN];
    #pragma unroll
    for (int j=0;j<SSN;j++){
        float a = b1[j];
        #pragma unroll
        for (int k=0;k<9;k++) a += f[k]*w1[k*SSN+j];
        h1[j] = fmaxf(a, 0.f);
    }
    #pragma unroll
    for (int j=0;j<SSN;j++){
        float a = b2[j];
        #pragma unroll
        for (int k=0;k<SSN;k++) a += h1[k]*w2[k*SSN+j];
        path_state[p*SSN+j] = fmaxf(a, 0.f);
    }
}

// ---------------- link/queue encoders + initial G (plane layout) ----------------
__global__ __launch_bounds__(64, 2) void k_link_init(
    const float* __restrict__ ft, const float* __restrict__ cap,
    const int* __restrict__ p2l, const int* __restrict__ btype,
    const float* __restrict__ lw1, const float* __restrict__ lb1,
    const float* __restrict__ lw2, const float* __restrict__ lb2,
    const float* __restrict__ qw1, const float* __restrict__ qb1,
    const float* __restrict__ qw2, const float* __restrict__ qb2,
    const float* __restrict__ pWxp, const float* __restrict__ pbi,
    float* __restrict__ link_state, float* __restrict__ queue_state,
    float* __restrict__ G)
{
    int l = blockIdx.x*64 + threadIdx.x; if (l >= LN) l = LN-1;
    float s = 0.f;
    #pragma unroll 8
    for (int dd=0; dd<DEGN; dd++) s += ft[p2l[(l*DEGN+dd)*2]];
    float load = s / cap[l];
    float t1[SSN], ls[SSN], qs[SSN];
    #pragma unroll
    for (int j=0;j<SSN;j++) t1[j] = fmaxf(load*lw1[j] + lb1[j], 0.f);
    #pragma unroll
    for (int j=0;j<SSN;j++){
        float a = lb2[j];
        #pragma unroll
        for (int k=0;k<SSN;k++) a += t1[k]*lw2[k*SSN+j];
        ls[j] = fmaxf(a, 0.f);
    }
    int bt = btype[l];
    #pragma unroll
    for (int j=0;j<SSN;j++) t1[j] = fmaxf(qw1[bt*SSN+j] + qb1[j], 0.f);
    #pragma unroll
    for (int j=0;j<SSN;j++){
        float a = qb2[j];
        #pragma unroll
        for (int k=0;k<SSN;k++) a += t1[k]*qw2[k*SSN+j];
        qs[j] = fmaxf(a, 0.f);
    }
    #pragma unroll
    for (int j=0;j<SSN;j++){ link_state[l*SSN+j]=ls[j]; queue_state[l*SSN+j]=qs[j]; }
    float x2[2*SSN];
    #pragma unroll
    for (int k=0;k<SSN;k++){ x2[k]=qs[k]; x2[SSN+k]=ls[k]; }
    #pragma unroll 1
    for (int j=0;j<SSN;j++){
        float a0=pbi[j], a1=pbi[SSN+j], a2=pbi[2*SSN+j];
        #pragma unroll
        for (int k=0;k<2*SSN;k++){
            const float* wv = pWxp + k*128 + j*4;
            a0 += x2[k]*wv[0]; a1 += x2[k]*wv[1]; a2 += x2[k]*wv[2];
        }
        G[l*96 + j] = a0; G[l*96 + SSN + j] = a1; G[l*96 + 2*SSN + j] = a2;
    }
}

// ---------------- path GRU scan: one path per 64-lane wave, k-split halves ----
// lane = (half, j): holds 48 weights in VGPRs, PINNED via opaque asm so the
// compiler cannot rematerialize the loads inside the hop loop (the R4/R5
// failure: VGPR_Count 84/48 = remat, ~3x instruction inflation).
__global__ __launch_bounds__(256, 4) void k_path_gru(
    const float* __restrict__ G, const int* __restrict__ l2p,
    const float* __restrict__ Whp, const float* __restrict__ bh,
    float* __restrict__ path_state, float* __restrict__ seq)
{
    int tid  = threadIdx.x;
    int wid  = tid >> 6;                 // wave in block [0,4)
    int lane = tid & 63;
    int j    = lane & 31;
    int half16 = (lane >> 5) << 4;       // 0 or 16
    int p = blockIdx.x*4 + wid;          // 12500*4 == 50000 exactly
    float w[48];
    {
        const float4* wp = (const float4*)(Whp + lane*48);
        #pragma unroll
        for (int q=0;q<12;q++){
            float4 v = wp[q];
            w[4*q]=v.x; w[4*q+1]=v.y; w[4*q+2]=v.z; w[4*q+3]=v.w;
        }
    }
    // pin: opaque to the optimizer -> must stay register-resident, no remat
    #pragma unroll
    for (int q=0;q<48;q++) asm volatile("" : "+v"(w[q]));
    float bz = bh[j], br = bh[SSN+j], bn = bh[2*SSN+j];
    asm volatile("" : "+v"(bz), "+v"(br), "+v"(bn));
    int links[HN];
    #pragma unroll
    for (int t=0;t<HN;t++) links[t] = l2p[p*HN+t];
    #pragma unroll
    for (int t=0;t<HN;t++) asm volatile("" : "+v"(links[t]));
    float hj = path_state[p*SSN + j];
    float grz = G[links[0]*96 + j];
    float grr = G[links[0]*96 + SSN + j];
    float grn = G[links[0]*96 + 2*SSN + j];
    #pragma unroll 1
    for (int t=0;t<HN;t++){
        int ln = links[(t+1) & 7];       // t=7 prefetch wasted but harmless
        float nz = G[ln*96 + j];
        float nr = G[ln*96 + SSN + j];
        float nn = G[ln*96 + 2*SSN + j];
        float az = 0.f, ar = 0.f, an = 0.f;
        #pragma unroll
        for (int k16=0;k16<16;k16++){
            float hk = __shfl(hj, half16 + k16, 32);  // group-local lane k holds h_k
            az += hk*w[k16*3+0];
            ar += hk*w[k16*3+1];
            an += hk*w[k16*3+2];
        }
        az += __shfl_xor(az, 32);
        ar += __shfl_xor(ar, 32);
        an += __shfl_xor(an, 32);
        float z = sig_(grz + bz + az);
        float r = sig_(grr + br + ar);
        float n = tanh_(grn + r*(an + bn));
        hj = z*hj + (1.0f-z)*n;
        if (lane < 32) seq[(p*HN+t)*SSN + j] = hj;
        grz = nz; grr = nr; grn = nn;
    }
    if (lane < 32) path_state[p*SSN + j] = hj;
}

// ---------------- queue GRU: wave per link ----------------
__global__ __launch_bounds__(64, 4) void k_queue_gru(
    const float* __restrict__ seq, const int* __restrict__ p2l,
    const float* __restrict__ Wxp, const float* __restrict__ Whp,
    const float* __restrict__ bi, const float* __restrict__ bhb,
    float* __restrict__ queue_state)
{
    __shared__ float red[DEGN][SSN+1];   // +1 pad: conflict-free column reads
    __shared__ float xsh[SSN];
    int l = blockIdx.x, d = threadIdx.x;
    int pp  = p2l[(l*DEGN+d)*2+0];
    int pos = p2l[(l*DEGN+d)*2+1];       // in [1,8]
    const float4* row = (const float4*)(seq + (pp*HN + pos - 1)*SSN);
    #pragma unroll
    for (int q=0;q<8;q++){
        float4 v = row[q];
        red[d][4*q]=v.x; red[d][4*q+1]=v.y; red[d][4*q+2]=v.z; red[d][4*q+3]=v.w;
    }
    __syncthreads();
    int j = d & 31;
    int base = (d < 32) ? 0 : 32;
    float xs = 0.f;
    #pragma unroll
    for (int dd=0; dd<32; dd++) xs += red[base+dd][j];
    xs += __shfl_xor(xs, 32);
    if (d < 32) xsh[j] = xs;
    __syncthreads();
    const float* hrow = queue_state + l*SSN;
    float hreg[SSN];
    #pragma unroll
    for (int k=0;k<SSN;k++) hreg[k] = hrow[k];
    float hj = hrow[j];
    float az = bi[j] + bhb[j];
    float ar = bi[SSN+j] + bhb[SSN+j];
    float xn = bi[2*SSN+j];
    float hn = bhb[2*SSN+j];
    #pragma unroll
    for (int k=0;k<SSN;k++){
        float xk = xsh[k], hk = hreg[k];
        float4 wx = *(const float4*)(Wxp + k*128 + j*4);
        float4 wh = *(const float4*)(Whp + k*128 + j*4);
        az += xk*wx.x + hk*wh.x;
        ar += xk*wx.y + hk*wh.y;
        xn += xk*wx.z;
        hn += hk*wh.z;
    }
    float z = sig_(az), r = sig_(ar);
    float n = tanh_(xn + r*hn);
    float outv = z*hj + (1.0f-z)*n;
    __syncthreads();
    queue_state[l*SSN+j] = outv;         // halves duplicate-write same value: benign
}

// ---------------- link GRU + next-iteration G (plane layout) ----------------
__global__ __launch_bounds__(64, 4) void k_link_gru(
    const float* __restrict__ queue_state, const int* __restrict__ q2l,
    const float* __restrict__ Wxp, const float* __restrict__ Whp,
    const float* __restrict__ bi, const float* __restrict__ bhb,
    const float* __restrict__ pWxp, const float* __restrict__ pbi,
    float* __restrict__ link_state, float* __restrict__ G)
{
    __shared__ float x2sh[2*SSN];
    int l = blockIdx.x, d = threadIdx.x, j = d & 31;
    int src = q2l[l];
    const float* xrow = queue_state + src*SSN;
    const float* hrow = link_state + l*SSN;
    float xreg[SSN], hreg[SSN];
    #pragma unroll
    for (int k=0;k<SSN;k++){ xreg[k]=xrow[k]; hreg[k]=hrow[k]; }
    float hj = hrow[j];
    float az = bi[j]+bhb[j], ar = bi[SSN+j]+bhb[SSN+j];
    float xn = bi[2*SSN+j], hn = bhb[2*SSN+j];
    #pragma unroll
    for (int k=0;k<SSN;k++){
        float4 wx = *(const float4*)(Wxp + k*128 + j*4);
        float4 wh = *(const float4*)(Whp + k*128 + j*4);
        az += xreg[k]*wx.x + hreg[k]*wh.x;
        ar += xreg[k]*wx.y + hreg[k]*wh.y;
        xn += xreg[k]*wx.z;
        hn += hreg[k]*wh.z;
    }
    float z = sig_(az), r = sig_(ar);
    float n = tanh_(xn + r*hn);
    float outv = z*hj + (1.0f-z)*n;
    link_state[l*SSN+j] = outv;
    if (d < 32){
        x2sh[j]     = queue_state[l*SSN+j];  // own (new) queue row
        x2sh[SSN+j] = outv;                  // own (new) link row
    }
    __syncthreads();
    float a0 = pbi[j], a1 = pbi[SSN+j], a2 = pbi[2*SSN+j];
    #pragma unroll
    for (int k=0;k<2*SSN;k++){
        float xk = x2sh[k];
        float4 wv = *(const float4*)(pWxp + k*128 + j*4);
        a0 += xk*wv.x; a1 += xk*wv.y; a2 += xk*wv.z;
    }
    G[l*96 + j] = a0; G[l*96 + SSN + j] = a1; G[l*96 + 2*SSN + j] = a2;
}

// ---------------- readout: thread per (path, hop), streaming low-VGPR form ----
__global__ __launch_bounds__(256, 4) void k_readout(
    const float* __restrict__ seq, const int* __restrict__ l2p,
    const float* __restrict__ cap, const float* __restrict__ ft,
    const float* __restrict__ fpk,
    const float* __restrict__ w1, const float* __restrict__ b1,
    const float* __restrict__ w2, const float* __restrict__ b2,
    const float* __restrict__ w3, const float* __restrict__ b3,
    float* __restrict__ out)
{
    int g = blockIdx.x*256 + threadIdx.x;
    int p = g >> 3, t = g & 7;
    if (p >= PN) p = PN-1;               // tail: duplicate same-value writes, benign
    int lk = l2p[p*HN + t];
    const float4* s4 = (const float4*)(seq + (p*HN+t)*SSN);
    float h1[16];
    #pragma unroll
    for (int j=0;j<16;j++) h1[j] = b1[j];
    #pragma unroll
    for (int q=0;q<8;q++){
        float4 v = s4[q];
        #pragma unroll
        for (int j=0;j<16;j++){
            h1[j] += v.x*w1[(4*q+0)*16+j] + v.y*w1[(4*q+1)*16+j]
                   + v.z*w1[(4*q+2)*16+j] + v.w*w1[(4*q+3)*16+j];
        }
    }
    #pragma unroll
    for (int j=0;j<16;j++) h1[j] = fmaxf(h1[j], 0.f);
    float h2[16];
    #pragma unroll
    for (int j=0;j<16;j++) h2[j] = b2[j];
    #pragma unroll
    for (int k=0;k<16;k++){
        float hk = h1[k];
        #pragma unroll
        for (int j=0;j<16;j++) h2[j] += hk*w2[k*16+j];
    }
    float occ = b3[0];
    #pragma unroll
    for (int k=0;k<16;k++) occ += fmaxf(h2[k], 0.f)*w3[k];
    float icg = rcp_(cap[lk]) * 1e-9f;
    float qd  = occ * icg;
    float inv = icg;
    qd  += __shfl_xor(qd, 1);  inv += __shfl_xor(inv, 1);
    qd  += __shfl_xor(qd, 2);  inv += __shfl_xor(inv, 2);
    qd  += __shfl_xor(qd, 4);  inv += __shfl_xor(inv, 4);
    if ((threadIdx.x & 7) == 0)
        out[p] = qd + ft[p]*rcp_(fpk[p])*inv;
}

extern "C" void kernel_launch(void* const* d_in, const int* in_sizes, int n_in,
                              void* d_out, int out_size, void* d_ws, size_t ws_size,
                              hipStream_t stream)
{
    (void)in_sizes; (void)n_in; (void)out_size; (void)ws_size;
    const float* ft    = (const float*)d_in[0];
    const float* fpk   = (const float*)d_in[1];
    const float* flam  = (const float*)d_in[2];
    const float* fob   = (const float*)d_in[3];
    const float* fon   = (const float*)d_in[4];
    const float* foff  = (const float*)d_in[5];
    const float* cap   = (const float*)d_in[6];
    const float* pe_w1 = (const float*)d_in[7];
    const float* pe_b1 = (const float*)d_in[8];
    const float* pe_w2 = (const float*)d_in[9];
    const float* pe_b2 = (const float*)d_in[10];
    const float* le_w1 = (const float*)d_in[11];
    const float* le_b1 = (const float*)d_in[12];
    const float* le_w2 = (const float*)d_in[13];
    const float* le_b2 = (const float*)d_in[14];
    const float* qe_w1 = (const float*)d_in[15];
    const float* qe_b1 = (const float*)d_in[16];
    const float* qe_w2 = (const float*)d_in[17];
    const float* qe_b2 = (const float*)d_in[18];
    const float* pWx   = (const float*)d_in[19];
    const float* pWh   = (const float*)d_in[20];
    const float* pbi   = (const float*)d_in[21];
    const float* pbh   = (const float*)d_in[22];
    const float* qWx   = (const float*)d_in[23];
    const float* qWh   = (const float*)d_in[24];
    const float* qbi   = (const float*)d_in[25];
    const float* qbh   = (const float*)d_in[26];
    const float* lWx   = (const float*)d_in[27];
    const float* lWh   = (const float*)d_in[28];
    const float* lbi   = (const float*)d_in[29];
    const float* lbh   = (const float*)d_in[30];
    const float* ro_w1 = (const float*)d_in[31];
    const float* ro_b1 = (const float*)d_in[32];
    const float* ro_w2 = (const float*)d_in[33];
    const float* ro_b2 = (const float*)d_in[34];
    const float* ro_w3 = (const float*)d_in[35];
    const float* ro_b3 = (const float*)d_in[36];
    const int* fdist = (const int*)d_in[37];
    const int* btype = (const int*)d_in[38];
    const int* l2p   = (const int*)d_in[39];
    const int* p2l   = (const int*)d_in[40];
    const int* q2l   = (const int*)d_in[41];

    float* ws = (float*)d_ws;
    float* pWhp = ws + OFF_PWHP;
    float* pWxp = ws + OFF_PWXP;
    float* qWxp = ws + OFF_QWXP;
    float* qWhp = ws + OFF_QWHP;
    float* lWxp = ws + OFF_LWXP;
    float* lWhp = ws + OFF_LWHP;
    float* path_state  = ws + OFF_PATH;
    float* seq         = ws + OFF_SEQ;
    float* queue_state = ws + OFF_QST;
    float* link_state  = ws + OFF_LST;
    float* G           = ws + OFF_G;

    k_pack<<<108, 256, 0, stream>>>(pWh, pWx, qWx, qWh, lWx, lWh, ws);
    k_path_init<<<(PN+255)/256, 256, 0, stream>>>(ft, fpk, flam, fob, fon, foff, fdist,
                                                  pe_w1, pe_b1, pe_w2, pe_b2, path_state);
    k_link_init<<<(LN+63)/64, 64, 0, stream>>>(ft, cap, p2l, btype,
                                               le_w1, le_b1, le_w2, le_b2,
                                               qe_w1, qe_b1, qe_w2, qe_b2,
                                               pWxp, pbi, link_state, queue_state, G);
    for (int it = 0; it < 8; ++it){
        k_path_gru<<<PN/4, 256, 0, stream>>>(G, l2p, pWhp, pbh, path_state, seq);
        k_queue_gru<<<LN, 64, 0, stream>>>(seq, p2l, qWxp, qWhp, qbi, qbh, queue_state);
        k_link_gru<<<LN, 64, 0, stream>>>(queue_state, q2l, lWxp, lWhp, lbi, lbh,
                                          pWxp, pbi, link_state, G);
    }
    k_readout<<<(PN*HN+255)/256, 256, 0, stream>>>(seq, l2p, cap, ft, fpk,
                                                   ro_w1, ro_b1, ro_w2, ro_b2, ro_w3, ro_b3,
                                                   (float*)d_out);
}

// Round 7
// 1407.878 us; speedup vs baseline: 1.0617x; 1.0617x over previous
//
#include <hip/hip_runtime.h>

#define PN 50000
#define LN 8000
#define HN 8
#define DEGN 64
#define SSN 32

// ---- fast-but-accurate nonlinearities (error ~1e-7 rel) ----
static __device__ __forceinline__ float rcp_(float x){ return __builtin_amdgcn_rcpf(x); }
static __device__ __forceinline__ float sig_(float x){ return rcp_(1.0f + __expf(-x)); }
static __device__ __forceinline__ float tanh_(float x){ return 1.0f - 2.0f*rcp_(__expf(2.0f*x) + 1.0f); }

// ws layout (float offsets)
#define OFF_PWHP 0          // path_Wh packed [lane(64)][k16(16)][3]  3072
#define OFF_PWXP 3072       // path_Wx packed [k][j][4]            8192
#define OFF_QWXP 11264      // queue_Wx packed [k][j][4]           4096
#define OFF_QWHP 15360      // queue_Wh packed [k][j][4]           4096
#define OFF_LWXP 19456      // link_Wx packed [k][j][4]            4096
#define OFF_LWHP 23552      // link_Wh packed [k][j][4]            4096
#define OFF_PATH 27648      // path_state (P,32)                   1600000
#define OFF_SEQ  1627648    // seq (P,8,32)                        12800000
#define OFF_QST  14427648   // queue_state (L,32)                  256000
#define OFF_LST  14683648   // link_state (L,32)                   256000
#define OFF_G    14939648   // G (L,96) plane layout [{z,r,n}][j]  768000
// total 15707648 floats = 62.8 MB

// ---------------- weight packing ----------------
__global__ __launch_bounds__(256) void k_pack(
    const float* __restrict__ pWh, const float* __restrict__ pWx,
    const float* __restrict__ qWx, const float* __restrict__ qWh,
    const float* __restrict__ lWx, const float* __restrict__ lWh,
    float* __restrict__ ws)
{
    int i = blockIdx.x*256 + threadIdx.x;
    int i0 = i;
    if (i0 < 3072){ // per-lane 48-weight layout: lane=(half*32+j), [k16][gate]
        int lane=i0/48, r=i0%48, k16=r/3, g=r%3;
        int half=lane>>5, j=lane&31;
        ws[OFF_PWHP+i0] = pWh[(half*16+k16)*96 + g*32 + j]; return; }
    i0 -= 3072;
    if (i0 < 8192){ int k=i0/128, r=i0%128, j=r/4, c=r%4;
        ws[OFF_PWXP+i0] = (c<3)? pWx[k*96 + c*32 + j] : 0.f; return; }
    i0 -= 8192;
    if (i0 < 4096){ int k=i0/128, r=i0%128, j=r/4, c=r%4;
        ws[OFF_QWXP+i0] = (c<3)? qWx[k*96 + c*32 + j] : 0.f; return; }
    i0 -= 4096;
    if (i0 < 4096){ int k=i0/128, r=i0%128, j=r/4, c=r%4;
        ws[OFF_QWHP+i0] = (c<3)? qWh[k*96 + c*32 + j] : 0.f; return; }
    i0 -= 4096;
    if (i0 < 4096){ int k=i0/128, r=i0%128, j=r/4, c=r%4;
        ws[OFF_LWXP+i0] = (c<3)? lWx[k*96 + c*32 + j] : 0.f; return; }
    i0 -= 4096;
    if (i0 < 4096){ int k=i0/128, r=i0%128, j=r/4, c=r%4;
        ws[OFF_LWHP+i0] = (c<3)? lWh[k*96 + c*32 + j] : 0.f; return; }
}

// ---------------- path encoder: path_state = mlp2(feats) ----------------
__global__ __launch_bounds__(256, 4) void k_path_init(
    const float* __restrict__ ft, const float* __restrict__ fpk,
    const float* __restrict__ flam, const float* __restrict__ fob,
    const float* __restrict__ fon, const float* __restrict__ foff,
    const int* __restrict__ fdist,
    const float* __restrict__ w1, const float* __restrict__ b1,
    const float* __restrict__ w2, const float* __restrict__ b2,
    float* __restrict__ path_state)
{
    int p = blockIdx.x*256 + threadIdx.x; if (p >= PN) p = PN-1;
    float f[9];
    f[0]=ft[p]; f[1]=fpk[p];
    int dcls = fdist[p];
    f[2] = (dcls==0)?1.f:0.f; f[3]=(dcls==1)?1.f:0.f; f[4]=(dcls==2)?1.f:0.f;
    f[5]=flam[p]; f[6]=fob[p]; f[7]=fon[p]; f[8]=foff[p];
    float h1[SSN];
    #pragma unroll
    for (int j=0;j<SSN;j++){
        float a = b1[j];
        #pragma unroll
        for (int k=0;k<9;k++) a += f[k]*w1[k*SSN+j];
        h1[j] = fmaxf(a, 0.f);
    }
    #pragma unroll
    for (int j=0;j<SSN;j++){
        float a = b2[j];
        #pragma unroll
        for (int k=0;k<SSN;k++) a += h1[k]*w2[k*SSN+j];
        path_state[p*SSN+j] = fmaxf(a, 0.f);
    }
}

// ---------------- link/queue encoders + initial G (plane layout) ----------------
__global__ __launch_bounds__(64, 2) void k_link_init(
    const float* __restrict__ ft, const float* __restrict__ cap,
    const int* __restrict__ p2l, const int* __restrict__ btype,
    const float* __restrict__ lw1, const float* __restrict__ lb1,
    const float* __restrict__ lw2, const float* __restrict__ lb2,
    const float* __restrict__ qw1, const float* __restrict__ qb1,
    const float* __restrict__ qw2, const float* __restrict__ qb2,
    const float* __restrict__ pWxp, const float* __restrict__ pbi,
    float* __restrict__ link_state, float* __restrict__ queue_state,
    float* __restrict__ G)
{
    int l = blockIdx.x*64 + threadIdx.x; if (l >= LN) l = LN-1;
    float s = 0.f;
    #pragma unroll 8
    for (int dd=0; dd<DEGN; dd++) s += ft[p2l[(l*DEGN+dd)*2]];
    float load = s / cap[l];
    float t1[SSN], ls[SSN], qs[SSN];
    #pragma unroll
    for (int j=0;j<SSN;j++) t1[j] = fmaxf(load*lw1[j] + lb1[j], 0.f);
    #pragma unroll
    for (int j=0;j<SSN;j++){
        float a = lb2[j];
        #pragma unroll
        for (int k=0;k<SSN;k++) a += t1[k]*lw2[k*SSN+j];
        ls[j] = fmaxf(a, 0.f);
    }
    int bt = btype[l];
    #pragma unroll
    for (int j=0;j<SSN;j++) t1[j] = fmaxf(qw1[bt*SSN+j] + qb1[j], 0.f);
    #pragma unroll
    for (int j=0;j<SSN;j++){
        float a = qb2[j];
        #pragma unroll
        for (int k=0;k<SSN;k++) a += t1[k]*qw2[k*SSN+j];
        qs[j] = fmaxf(a, 0.f);
    }
    #pragma unroll
    for (int j=0;j<SSN;j++){ link_state[l*SSN+j]=ls[j]; queue_state[l*SSN+j]=qs[j]; }
    float x2[2*SSN];
    #pragma unroll
    for (int k=0;k<SSN;k++){ x2[k]=qs[k]; x2[SSN+k]=ls[k]; }
    #pragma unroll 1
    for (int j=0;j<SSN;j++){
        float a0=pbi[j], a1=pbi[SSN+j], a2=pbi[2*SSN+j];
        #pragma unroll
        for (int k=0;k<2*SSN;k++){
            const float* wv = pWxp + k*128 + j*4;
            a0 += x2[k]*wv[0]; a1 += x2[k]*wv[1]; a2 += x2[k]*wv[2];
        }
        G[l*96 + j] = a0; G[l*96 + SSN + j] = a1; G[l*96 + 2*SSN + j] = a2;
    }
}

// ---------------- path GRU scan: one path per 64-lane wave, k-split halves ----
// Fixes vs R6: (a) amdgpu_waves_per_eu(4,4) pins the allocator's occupancy
// target at 4 waves/EU (128-VGPR budget) so pinned weights neither remat nor
// spill; (b) raw ds_bpermute with HOP-INVARIANT precomputed byte addresses
// replaces __shfl(.,32) (whose width-masking lowering cost ~5 inst/shuffle).
__global__ __launch_bounds__(256)
__attribute__((amdgpu_waves_per_eu(4,4)))
void k_path_gru(
    const float* __restrict__ G, const int* __restrict__ l2p,
    const float* __restrict__ Whp, const float* __restrict__ bh,
    float* __restrict__ path_state, float* __restrict__ seq)
{
    int tid  = threadIdx.x;
    int wid  = tid >> 6;                 // wave in block [0,4)
    int lane = tid & 63;
    int j    = lane & 31;
    int half16 = (lane >> 5) << 4;       // 0 or 16
    int p = blockIdx.x*4 + wid;          // 12500*4 == 50000 exactly
    float w[48];
    {
        const float4* wp = (const float4*)(Whp + lane*48);
        #pragma unroll
        for (int q=0;q<12;q++){
            float4 v = wp[q];
            w[4*q]=v.x; w[4*q+1]=v.y; w[4*q+2]=v.z; w[4*q+3]=v.w;
        }
    }
    #pragma unroll
    for (int q=0;q<48;q++) asm volatile("" : "+v"(w[q]));
    // hop-invariant bpermute byte addresses (both halves hold identical h,
    // so a plain wave64 bpermute from lane half16+k16 is correct)
    int baddr[16];
    #pragma unroll
    for (int k16=0;k16<16;k16++) baddr[k16] = (half16 + k16) << 2;
    #pragma unroll
    for (int k16=0;k16<16;k16++) asm volatile("" : "+v"(baddr[k16]));
    int xaddr = (lane ^ 32) << 2;        // cross-half partial-sum exchange
    asm volatile("" : "+v"(xaddr));
    float bz = bh[j], br = bh[SSN+j], bn = bh[2*SSN+j];
    asm volatile("" : "+v"(bz), "+v"(br), "+v"(bn));
    int links[HN];
    #pragma unroll
    for (int t=0;t<HN;t++) links[t] = l2p[p*HN+t];
    #pragma unroll
    for (int t=0;t<HN;t++) asm volatile("" : "+v"(links[t]));
    float hj = path_state[p*SSN + j];
    float grz = G[links[0]*96 + j];
    float grr = G[links[0]*96 + SSN + j];
    float grn = G[links[0]*96 + 2*SSN + j];
    #pragma unroll 1
    for (int t=0;t<HN;t++){
        int ln = links[(t+1) & 7];       // t=7 prefetch wasted but harmless
        float nz = G[ln*96 + j];
        float nr = G[ln*96 + SSN + j];
        float nn = G[ln*96 + 2*SSN + j];
        float hk[16];
        #pragma unroll
        for (int k16=0;k16<16;k16++)
            hk[k16] = __int_as_float(__builtin_amdgcn_ds_bpermute(baddr[k16], __float_as_int(hj)));
        float az = 0.f, ar = 0.f, an = 0.f;
        #pragma unroll
        for (int k16=0;k16<16;k16++){
            az += hk[k16]*w[k16*3+0];
            ar += hk[k16]*w[k16*3+1];
            an += hk[k16]*w[k16*3+2];
        }
        az += __int_as_float(__builtin_amdgcn_ds_bpermute(xaddr, __float_as_int(az)));
        ar += __int_as_float(__builtin_amdgcn_ds_bpermute(xaddr, __float_as_int(ar)));
        an += __int_as_float(__builtin_amdgcn_ds_bpermute(xaddr, __float_as_int(an)));
        float z = sig_(grz + bz + az);
        float r = sig_(grr + br + ar);
        float n = tanh_(grn + r*(an + bn));
        hj = z*hj + (1.0f-z)*n;
        if (lane < 32) seq[(p*HN+t)*SSN + j] = hj;
        grz = nz; grr = nr; grn = nn;
    }
    if (lane < 32) path_state[p*SSN + j] = hj;
}

// ---------------- queue GRU: wave per link ----------------
__global__ __launch_bounds__(64, 4) void k_queue_gru(
    const float* __restrict__ seq, const int* __restrict__ p2l,
    const float* __restrict__ Wxp, const float* __restrict__ Whp,
    const float* __restrict__ bi, const float* __restrict__ bhb,
    float* __restrict__ queue_state)
{
    __shared__ float red[DEGN][SSN+1];   // +1 pad: conflict-free column reads
    __shared__ float xsh[SSN];
    int l = blockIdx.x, d = threadIdx.x;
    int pp  = p2l[(l*DEGN+d)*2+0];
    int pos = p2l[(l*DEGN+d)*2+1];       // in [1,8]
    const float4* row = (const float4*)(seq + (pp*HN + pos - 1)*SSN);
    #pragma unroll
    for (int q=0;q<8;q++){
        float4 v = row[q];
        red[d][4*q]=v.x; red[d][4*q+1]=v.y; red[d][4*q+2]=v.z; red[d][4*q+3]=v.w;
    }
    __syncthreads();
    int j = d & 31;
    int base = (d < 32) ? 0 : 32;
    float xs = 0.f;
    #pragma unroll
    for (int dd=0; dd<32; dd++) xs += red[base+dd][j];
    xs += __shfl_xor(xs, 32);
    if (d < 32) xsh[j] = xs;
    __syncthreads();
    const float* hrow = queue_state + l*SSN;
    float hreg[SSN];
    #pragma unroll
    for (int k=0;k<SSN;k++) hreg[k] = hrow[k];
    float hj = hrow[j];
    float az = bi[j] + bhb[j];
    float ar = bi[SSN+j] + bhb[SSN+j];
    float xn = bi[2*SSN+j];
    float hn = bhb[2*SSN+j];
    #pragma unroll
    for (int k=0;k<SSN;k++){
        float xk = xsh[k], hk = hreg[k];
        float4 wx = *(const float4*)(Wxp + k*128 + j*4);
        float4 wh = *(const float4*)(Whp + k*128 + j*4);
        az += xk*wx.x + hk*wh.x;
        ar += xk*wx.y + hk*wh.y;
        xn += xk*wx.z;
        hn += hk*wh.z;
    }
    float z = sig_(az), r = sig_(ar);
    float n = tanh_(xn + r*hn);
    float outv = z*hj + (1.0f-z)*n;
    __syncthreads();
    queue_state[l*SSN+j] = outv;         // halves duplicate-write same value: benign
}

// ---------------- link GRU + next-iteration G (plane layout) ----------------
__global__ __launch_bounds__(64, 4) void k_link_gru(
    const float* __restrict__ queue_state, const int* __restrict__ q2l,
    const float* __restrict__ Wxp, const float* __restrict__ Whp,
    const float* __restrict__ bi, const float* __restrict__ bhb,
    const float* __restrict__ pWxp, const float* __restrict__ pbi,
    float* __restrict__ link_state, float* __restrict__ G)
{
    __shared__ float x2sh[2*SSN];
    int l = blockIdx.x, d = threadIdx.x, j = d & 31;
    int src = q2l[l];
    const float* xrow = queue_state + src*SSN;
    const float* hrow = link_state + l*SSN;
    float xreg[SSN], hreg[SSN];
    #pragma unroll
    for (int k=0;k<SSN;k++){ xreg[k]=xrow[k]; hreg[k]=hrow[k]; }
    float hj = hrow[j];
    float az = bi[j]+bhb[j], ar = bi[SSN+j]+bhb[SSN+j];
    float xn = bi[2*SSN+j], hn = bhb[2*SSN+j];
    #pragma unroll
    for (int k=0;k<SSN;k++){
        float4 wx = *(const float4*)(Wxp + k*128 + j*4);
        float4 wh = *(const float4*)(Whp + k*128 + j*4);
        az += xreg[k]*wx.x + hreg[k]*wh.x;
        ar += xreg[k]*wx.y + hreg[k]*wh.y;
        xn += xreg[k]*wx.z;
        hn += hreg[k]*wh.z;
    }
    float z = sig_(az), r = sig_(ar);
    float n = tanh_(xn + r*hn);
    float outv = z*hj + (1.0f-z)*n;
    link_state[l*SSN+j] = outv;
    if (d < 32){
        x2sh[j]     = queue_state[l*SSN+j];  // own (new) queue row
        x2sh[SSN+j] = outv;                  // own (new) link row
    }
    __syncthreads();
    float a0 = pbi[j], a1 = pbi[SSN+j], a2 = pbi[2*SSN+j];
    #pragma unroll
    for (int k=0;k<2*SSN;k++){
        float xk = x2sh[k];
        float4 wv = *(const float4*)(pWxp + k*128 + j*4);
        a0 += xk*wv.x; a1 += xk*wv.y; a2 += xk*wv.z;
    }
    G[l*96 + j] = a0; G[l*96 + SSN + j] = a1; G[l*96 + 2*SSN + j] = a2;
}

// ---------------- readout: thread per (path, hop), streaming low-VGPR form ----
__global__ __launch_bounds__(256, 4) void k_readout(
    const float* __restrict__ seq, const int* __restrict__ l2p,
    const float* __restrict__ cap, const float* __restrict__ ft,
    const float* __restrict__ fpk,
    const float* __restrict__ w1, const float* __restrict__ b1,
    const float* __restrict__ w2, const float* __restrict__ b2,
    const float* __restrict__ w3, const float* __restrict__ b3,
    float* __restrict__ out)
{
    int g = blockIdx.x*256 + threadIdx.x;
    int p = g >> 3, t = g & 7;
    if (p >= PN) p = PN-1;               // tail: duplicate same-value writes, benign
    int lk = l2p[p*HN + t];
    const float4* s4 = (const float4*)(seq + (p*HN+t)*SSN);
    float h1[16];
    #pragma unroll
    for (int j=0;j<16;j++) h1[j] = b1[j];
    #pragma unroll
    for (int q=0;q<8;q++){
        float4 v = s4[q];
        #pragma unroll
        for (int j=0;j<16;j++){
            h1[j] += v.x*w1[(4*q+0)*16+j] + v.y*w1[(4*q+1)*16+j]
                   + v.z*w1[(4*q+2)*16+j] + v.w*w1[(4*q+3)*16+j];
        }
    }
    #pragma unroll
    for (int j=0;j<16;j++) h1[j] = fmaxf(h1[j], 0.f);
    float h2[16];
    #pragma unroll
    for (int j=0;j<16;j++) h2[j] = b2[j];
    #pragma unroll
    for (int k=0;k<16;k++){
        float hk = h1[k];
        #pragma unroll
        for (int j=0;j<16;j++) h2[j] += hk*w2[k*16+j];
    }
    float occ = b3[0];
    #pragma unroll
    for (int k=0;k<16;k++) occ += fmaxf(h2[k], 0.f)*w3[k];
    float icg = rcp_(cap[lk]) * 1e-9f;
    float qd  = occ * icg;
    float inv = icg;
    qd  += __shfl_xor(qd, 1);  inv += __shfl_xor(inv, 1);
    qd  += __shfl_xor(qd, 2);  inv += __shfl_xor(inv, 2);
    qd  += __shfl_xor(qd, 4);  inv += __shfl_xor(inv, 4);
    if ((threadIdx.x & 7) == 0)
        out[p] = qd + ft[p]*rcp_(fpk[p])*inv;
}

extern "C" void kernel_launch(void* const* d_in, const int* in_sizes, int n_in,
                              void* d_out, int out_size, void* d_ws, size_t ws_size,
                              hipStream_t stream)
{
    (void)in_sizes; (void)n_in; (void)out_size; (void)ws_size;
    const float* ft    = (const float*)d_in[0];
    const float* fpk   = (const float*)d_in[1];
    const float* flam  = (const float*)d_in[2];
    const float* fob   = (const float*)d_in[3];
    const float* fon   = (const float*)d_in[4];
    const float* foff  = (const float*)d_in[5];
    const float* cap   = (const float*)d_in[6];
    const float* pe_w1 = (const float*)d_in[7];
    const float* pe_b1 = (const float*)d_in[8];
    const float* pe_w2 = (const float*)d_in[9];
    const float* pe_b2 = (const float*)d_in[10];
    const float* le_w1 = (const float*)d_in[11];
    const float* le_b1 = (const float*)d_in[12];
    const float* le_w2 = (const float*)d_in[13];
    const float* le_b2 = (const float*)d_in[14];
    const float* qe_w1 = (const float*)d_in[15];
    const float* qe_b1 = (const float*)d_in[16];
    const float* qe_w2 = (const float*)d_in[17];
    const float* qe_b2 = (const float*)d_in[18];
    const float* pWx   = (const float*)d_in[19];
    const float* pWh   = (const float*)d_in[20];
    const float* pbi   = (const float*)d_in[21];
    const float* pbh   = (const float*)d_in[22];
    const float* qWx   = (const float*)d_in[23];
    const float* qWh   = (const float*)d_in[24];
    const float* qbi   = (const float*)d_in[25];
    const float* qbh   = (const float*)d_in[26];
    const float* lWx   = (const float*)d_in[27];
    const float* lWh   = (const float*)d_in[28];
    const float* lbi   = (const float*)d_in[29];
    const float* lbh   = (const float*)d_in[30];
    const float* ro_w1 = (const float*)d_in[31];
    const float* ro_b1 = (const float*)d_in[32];
    const float* ro_w2 = (const float*)d_in[33];
    const float* ro_b2 = (const float*)d_in[34];
    const float* ro_w3 = (const float*)d_in[35];
    const float* ro_b3 = (const float*)d_in[36];
    const int* fdist = (const int*)d_in[37];
    const int* btype = (const int*)d_in[38];
    const int* l2p   = (const int*)d_in[39];
    const int* p2l   = (const int*)d_in[40];
    const int* q2l   = (const int*)d_in[41];

    float* ws = (float*)d_ws;
    float* pWhp = ws + OFF_PWHP;
    float* pWxp = ws + OFF_PWXP;
    float* qWxp = ws + OFF_QWXP;
    float* qWhp = ws + OFF_QWHP;
    float* lWxp = ws + OFF_LWXP;
    float* lWhp = ws + OFF_LWHP;
    float* path_state  = ws + OFF_PATH;
    float* seq         = ws + OFF_SEQ;
    float* queue_state = ws + OFF_QST;
    float* link_state  = ws + OFF_LST;
    float* G           = ws + OFF_G;

    k_pack<<<108, 256, 0, stream>>>(pWh, pWx, qWx, qWh, lWx, lWh, ws);
    k_path_init<<<(PN+255)/256, 256, 0, stream>>>(ft, fpk, flam, fob, fon, foff, fdist,
                                                  pe_w1, pe_b1, pe_w2, pe_b2, path_state);
    k_link_init<<<(LN+63)/64, 64, 0, stream>>>(ft, cap, p2l, btype,
                                               le_w1, le_b1, le_w2, le_b2,
                                               qe_w1, qe_b1, qe_w2, qe_b2,
                                               pWxp, pbi, link_state, queue_state, G);
    for (int it = 0; it < 8; ++it){
        k_path_gru<<<PN/4, 256, 0, stream>>>(G, l2p, pWhp, pbh, path_state, seq);
        k_queue_gru<<<LN, 64, 0, stream>>>(seq, p2l, qWxp, qWhp, qbi, qbh, queue_state);
        k_link_gru<<<LN, 64, 0, stream>>>(queue_state, q2l, lWxp, lWhp, lbi, lbh,
                                          pWxp, pbi, link_state, G);
    }
    k_readout<<<(PN*HN+255)/256, 256, 0, stream>>>(seq, l2p, cap, ft, fpk,
                                                   ro_w1, ro_b1, ro_w2, ro_b2, ro_w3, ro_b3,
                                                   (float*)d_out);
}

// Round 8
// 1299.038 us; speedup vs baseline: 1.1506x; 1.0838x over previous
//
#include <hip/hip_runtime.h>

#define PN 50000
#define LN 8000
#define HN 8
#define DEGN 64
#define SSN 32

// ---- fast-but-accurate nonlinearities (error ~1e-7 rel) ----
static __device__ __forceinline__ float rcp_(float x){ return __builtin_amdgcn_rcpf(x); }
static __device__ __forceinline__ float sig_(float x){ return rcp_(1.0f + __expf(-x)); }
static __device__ __forceinline__ float tanh_(float x){ return 1.0f - 2.0f*rcp_(__expf(2.0f*x) + 1.0f); }

// ws layout (float offsets)
#define OFF_PWHP 0          // path_Wh packed [lane(64)][k16(16)][3]  3072
#define OFF_PWXP 3072       // path_Wx packed [k][j][4]            8192
#define OFF_QWXP 11264      // queue_Wx packed [k][j][4]           4096
#define OFF_QWHP 15360      // queue_Wh packed [k][j][4]           4096
#define OFF_LWXP 19456      // link_Wx packed [k][j][4]            4096
#define OFF_LWHP 23552      // link_Wh packed [k][j][4]            4096
#define OFF_PATH 27648      // path_state (P,32)                   1600000
#define OFF_SEQ  1627648    // seq (P,8,32)                        12800000
#define OFF_QST  14427648   // queue_state (L,32)                  256000
#define OFF_LST  14683648   // link_state (L,32)                   256000
#define OFF_G    14939648   // G (L,96) plane layout [{z,r,n}][j]  768000
// total 15707648 floats = 62.8 MB

// ---------------- weight packing ----------------
__global__ __launch_bounds__(256) void k_pack(
    const float* __restrict__ pWh, const float* __restrict__ pWx,
    const float* __restrict__ qWx, const float* __restrict__ qWh,
    const float* __restrict__ lWx, const float* __restrict__ lWh,
    float* __restrict__ ws)
{
    int i = blockIdx.x*256 + threadIdx.x;
    int i0 = i;
    if (i0 < 3072){ // per-lane 48-weight layout: lane=(half*32+j), [k16][gate]
        int lane=i0/48, r=i0%48, k16=r/3, g=r%3;
        int half=lane>>5, j=lane&31;
        ws[OFF_PWHP+i0] = pWh[(half*16+k16)*96 + g*32 + j]; return; }
    i0 -= 3072;
    if (i0 < 8192){ int k=i0/128, r=i0%128, j=r/4, c=r%4;
        ws[OFF_PWXP+i0] = (c<3)? pWx[k*96 + c*32 + j] : 0.f; return; }
    i0 -= 8192;
    if (i0 < 4096){ int k=i0/128, r=i0%128, j=r/4, c=r%4;
        ws[OFF_QWXP+i0] = (c<3)? qWx[k*96 + c*32 + j] : 0.f; return; }
    i0 -= 4096;
    if (i0 < 4096){ int k=i0/128, r=i0%128, j=r/4, c=r%4;
        ws[OFF_QWHP+i0] = (c<3)? qWh[k*96 + c*32 + j] : 0.f; return; }
    i0 -= 4096;
    if (i0 < 4096){ int k=i0/128, r=i0%128, j=r/4, c=r%4;
        ws[OFF_LWXP+i0] = (c<3)? lWx[k*96 + c*32 + j] : 0.f; return; }
    i0 -= 4096;
    if (i0 < 4096){ int k=i0/128, r=i0%128, j=r/4, c=r%4;
        ws[OFF_LWHP+i0] = (c<3)? lWh[k*96 + c*32 + j] : 0.f; return; }
}

// ---------------- path encoder: path_state = mlp2(feats) ----------------
__global__ __launch_bounds__(256, 4) void k_path_init(
    const float* __restrict__ ft, const float* __restrict__ fpk,
    const float* __restrict__ flam, const float* __restrict__ fob,
    const float* __restrict__ fon, const float* __restrict__ foff,
    const int* __restrict__ fdist,
    const float* __restrict__ w1, const float* __restrict__ b1,
    const float* __restrict__ w2, const float* __restrict__ b2,
    float* __restrict__ path_state)
{
    int p = blockIdx.x*256 + threadIdx.x; if (p >= PN) p = PN-1;
    float f[9];
    f[0]=ft[p]; f[1]=fpk[p];
    int dcls = fdist[p];
    f[2] = (dcls==0)?1.f:0.f; f[3]=(dcls==1)?1.f:0.f; f[4]=(dcls==2)?1.f:0.f;
    f[5]=flam[p]; f[6]=fob[p]; f[7]=fon[p]; f[8]=foff[p];
    float h1[SSN];
    #pragma unroll
    for (int j=0;j<SSN;j++){
        float a = b1[j];
        #pragma unroll
        for (int k=0;k<9;k++) a += f[k]*w1[k*SSN+j];
        h1[j] = fmaxf(a, 0.f);
    }
    #pragma unroll
    for (int j=0;j<SSN;j++){
        float a = b2[j];
        #pragma unroll
        for (int k=0;k<SSN;k++) a += h1[k]*w2[k*SSN+j];
        path_state[p*SSN+j] = fmaxf(a, 0.f);
    }
}

// ---------------- link/queue encoders + initial G (plane layout) ----------------
__global__ __launch_bounds__(64, 2) void k_link_init(
    const float* __restrict__ ft, const float* __restrict__ cap,
    const int* __restrict__ p2l, const int* __restrict__ btype,
    const float* __restrict__ lw1, const float* __restrict__ lb1,
    const float* __restrict__ lw2, const float* __restrict__ lb2,
    const float* __restrict__ qw1, const float* __restrict__ qb1,
    const float* __restrict__ qw2, const float* __restrict__ qb2,
    const float* __restrict__ pWxp, const float* __restrict__ pbi,
    float* __restrict__ link_state, float* __restrict__ queue_state,
    float* __restrict__ G)
{
    int l = blockIdx.x*64 + threadIdx.x; if (l >= LN) l = LN-1;
    float s = 0.f;
    #pragma unroll 8
    for (int dd=0; dd<DEGN; dd++) s += ft[p2l[(l*DEGN+dd)*2]];
    float load = s / cap[l];
    float t1[SSN], ls[SSN], qs[SSN];
    #pragma unroll
    for (int j=0;j<SSN;j++) t1[j] = fmaxf(load*lw1[j] + lb1[j], 0.f);
    #pragma unroll
    for (int j=0;j<SSN;j++){
        float a = lb2[j];
        #pragma unroll
        for (int k=0;k<SSN;k++) a += t1[k]*lw2[k*SSN+j];
        ls[j] = fmaxf(a, 0.f);
    }
    int bt = btype[l];
    #pragma unroll
    for (int j=0;j<SSN;j++) t1[j] = fmaxf(qw1[bt*SSN+j] + qb1[j], 0.f);
    #pragma unroll
    for (int j=0;j<SSN;j++){
        float a = qb2[j];
        #pragma unroll
        for (int k=0;k<SSN;k++) a += t1[k]*qw2[k*SSN+j];
        qs[j] = fmaxf(a, 0.f);
    }
    #pragma unroll
    for (int j=0;j<SSN;j++){ link_state[l*SSN+j]=ls[j]; queue_state[l*SSN+j]=qs[j]; }
    float x2[2*SSN];
    #pragma unroll
    for (int k=0;k<SSN;k++){ x2[k]=qs[k]; x2[SSN+k]=ls[k]; }
    #pragma unroll 1
    for (int j=0;j<SSN;j++){
        float a0=pbi[j], a1=pbi[SSN+j], a2=pbi[2*SSN+j];
        #pragma unroll
        for (int k=0;k<2*SSN;k++){
            const float* wv = pWxp + k*128 + j*4;
            a0 += x2[k]*wv[0]; a1 += x2[k]*wv[1]; a2 += x2[k]*wv[2];
        }
        G[l*96 + j] = a0; G[l*96 + SSN + j] = a1; G[l*96 + 2*SSN + j] = a2;
    }
}

// ---------------- path GRU scan: one path per 64-lane wave, k-split halves ----
// R8: NO pins, NO runtime-indexed arrays (8-hop loop FULLY unrolled; links via
// two static int4 loads), raw wave64 ds_bpermute with loop-invariant base +
// constant offsets, waves_per_eu(4,4) for a 128-VGPR budget. Goal: w[48] truly
// register-resident with zero scratch.
__global__ __launch_bounds__(256)
__attribute__((amdgpu_waves_per_eu(4,4)))
void k_path_gru(
    const float* __restrict__ G, const int* __restrict__ l2p,
    const float* __restrict__ Whp, const float* __restrict__ bh,
    float* __restrict__ path_state, float* __restrict__ seq)
{
    const int tid  = threadIdx.x;
    const int lane = tid & 63;
    const int j    = lane & 31;
    const int hbase = (lane >> 5) << 6;   // byte addr: lane 0-31 read lanes 0-15; 32-63 read 16-31
    const int xaddr = (lane ^ 32) << 2;   // cross-half exchange
    const int p = blockIdx.x*4 + (tid >> 6);   // 12500*4 == 50000
    float w[48];
    {
        const float4* wp = (const float4*)(Whp + lane*48);
        #pragma unroll
        for (int q=0;q<12;q++){
            float4 v = wp[q];
            w[4*q]=v.x; w[4*q+1]=v.y; w[4*q+2]=v.z; w[4*q+3]=v.w;
        }
    }
    const float bz = bh[j], br = bh[SSN+j], bn = bh[2*SSN+j];
    const int4 la = *(const int4*)(l2p + p*HN);
    const int4 lb = *(const int4*)(l2p + p*HN + 4);
    float hj = path_state[p*SSN + j];
    float cz, cr, cn, nz, nr, nn;
    { const float* g = G + la.x*96; cz=g[j]; cr=g[SSN+j]; cn=g[2*SSN+j]; }

#define PF(L_) { const float* g = G + (L_)*96; nz=g[j]; nr=g[SSN+j]; nn=g[2*SSN+j]; }
#define HOP(T_) { \
    float az0=0.f,ar0=0.f,an0=0.f,az1=0.f,ar1=0.f,an1=0.f; \
    _Pragma("unroll") \
    for (int k=0;k<16;k+=2){ \
        float h0 = __int_as_float(__builtin_amdgcn_ds_bpermute(hbase + 4*k,     __float_as_int(hj))); \
        float h1 = __int_as_float(__builtin_amdgcn_ds_bpermute(hbase + 4*k + 4, __float_as_int(hj))); \
        az0 += h0*w[3*k+0]; ar0 += h0*w[3*k+1]; an0 += h0*w[3*k+2]; \
        az1 += h1*w[3*k+3]; ar1 += h1*w[3*k+4]; an1 += h1*w[3*k+5]; \
    } \
    float az=az0+az1, ar=ar0+ar1, an=an0+an1; \
    az += __int_as_float(__builtin_amdgcn_ds_bpermute(xaddr, __float_as_int(az))); \
    ar += __int_as_float(__builtin_amdgcn_ds_bpermute(xaddr, __float_as_int(ar))); \
    an += __int_as_float(__builtin_amdgcn_ds_bpermute(xaddr, __float_as_int(an))); \
    float z = sig_(cz + bz + az); \
    float r = sig_(cr + br + ar); \
    float n = tanh_(cn + r*(an + bn)); \
    hj = z*hj + (1.0f-z)*n; \
    if (lane < SSN) seq[(p*HN+T_)*SSN + j] = hj; \
    cz = nz; cr = nr; cn = nn; }

    PF(la.y) HOP(0)
    PF(la.z) HOP(1)
    PF(la.w) HOP(2)
    PF(lb.x) HOP(3)
    PF(lb.y) HOP(4)
    PF(lb.z) HOP(5)
    PF(lb.w) HOP(6)
    HOP(7)
#undef PF
#undef HOP
    if (lane < SSN) path_state[p*SSN + j] = hj;
}

// ---------------- queue GRU: wave per link, 4 links per block ----------------
__global__ __launch_bounds__(256) void k_queue_gru(
    const float* __restrict__ seq, const int* __restrict__ p2l,
    const float* __restrict__ Wxp, const float* __restrict__ Whp,
    const float* __restrict__ bi, const float* __restrict__ bhb,
    float* __restrict__ queue_state)
{
    __shared__ float red[4][DEGN][SSN+1];   // +1 pad: conflict-free column reads
    __shared__ float xsh[4][SSN];
    int wid = threadIdx.x >> 6, d = threadIdx.x & 63;
    int l = blockIdx.x*4 + wid;
    int pp  = p2l[(l*DEGN+d)*2+0];
    int pos = p2l[(l*DEGN+d)*2+1];       // in [1,8]
    const float4* row = (const float4*)(seq + (pp*HN + pos - 1)*SSN);
    #pragma unroll
    for (int q=0;q<8;q++){
        float4 v = row[q];
        red[wid][d][4*q]=v.x; red[wid][d][4*q+1]=v.y; red[wid][d][4*q+2]=v.z; red[wid][d][4*q+3]=v.w;
    }
    __syncthreads();
    int j = d & 31;
    int base = (d < 32) ? 0 : 32;
    float xs = 0.f;
    #pragma unroll
    for (int dd=0; dd<32; dd++) xs += red[wid][base+dd][j];
    xs += __shfl_xor(xs, 32);
    if (d < 32) xsh[wid][j] = xs;
    __syncthreads();
    const float* hrow = queue_state + l*SSN;
    float hreg[SSN];
    #pragma unroll
    for (int k=0;k<SSN;k++) hreg[k] = hrow[k];
    float hj = hrow[j];
    float az = bi[j] + bhb[j];
    float ar = bi[SSN+j] + bhb[SSN+j];
    float xn = bi[2*SSN+j];
    float hn = bhb[2*SSN+j];
    #pragma unroll
    for (int k=0;k<SSN;k++){
        float xk = xsh[wid][k], hk = hreg[k];
        float4 wx = *(const float4*)(Wxp + k*128 + j*4);
        float4 wh = *(const float4*)(Whp + k*128 + j*4);
        az += xk*wx.x + hk*wh.x;
        ar += xk*wx.y + hk*wh.y;
        xn += xk*wx.z;
        hn += hk*wh.z;
    }
    float z = sig_(az), r = sig_(ar);
    float n = tanh_(xn + r*hn);
    float outv = z*hj + (1.0f-z)*n;
    __syncthreads();
    queue_state[l*SSN+j] = outv;         // halves duplicate-write same value: benign
}

// ---------------- link GRU + next-iteration G, 4 links per block -------------
__global__ __launch_bounds__(256) void k_link_gru(
    const float* __restrict__ queue_state, const int* __restrict__ q2l,
    const float* __restrict__ Wxp, const float* __restrict__ Whp,
    const float* __restrict__ bi, const float* __restrict__ bhb,
    const float* __restrict__ pWxp, const float* __restrict__ pbi,
    float* __restrict__ link_state, float* __restrict__ G)
{
    __shared__ float x2sh[4][2*SSN];
    int wid = threadIdx.x >> 6, d = threadIdx.x & 63, j = d & 31;
    int l = blockIdx.x*4 + wid;
    int src = q2l[l];
    const float* xrow = queue_state + src*SSN;
    const float* hrow = link_state + l*SSN;
    float xreg[SSN], hreg[SSN];
    #pragma unroll
    for (int k=0;k<SSN;k++){ xreg[k]=xrow[k]; hreg[k]=hrow[k]; }
    float hj = hrow[j];
    float az = bi[j]+bhb[j], ar = bi[SSN+j]+bhb[SSN+j];
    float xn = bi[2*SSN+j], hn = bhb[2*SSN+j];
    #pragma unroll
    for (int k=0;k<SSN;k++){
        float4 wx = *(const float4*)(Wxp + k*128 + j*4);
        float4 wh = *(const float4*)(Whp + k*128 + j*4);
        az += xreg[k]*wx.x + hreg[k]*wh.x;
        ar += xreg[k]*wx.y + hreg[k]*wh.y;
        xn += xreg[k]*wx.z;
        hn += hreg[k]*wh.z;
    }
    float z = sig_(az), r = sig_(ar);
    float n = tanh_(xn + r*hn);
    float outv = z*hj + (1.0f-z)*n;
    link_state[l*SSN+j] = outv;
    if (d < 32){
        x2sh[wid][j]     = queue_state[l*SSN+j];  // own (new) queue row
        x2sh[wid][SSN+j] = outv;                  // own (new) link row
    }
    __syncthreads();
    float a0 = pbi[j], a1 = pbi[SSN+j], a2 = pbi[2*SSN+j];
    #pragma unroll
    for (int k=0;k<2*SSN;k++){
        float xk = x2sh[wid][k];
        float4 wv = *(const float4*)(pWxp + k*128 + j*4);
        a0 += xk*wv.x; a1 += xk*wv.y; a2 += xk*wv.z;
    }
    G[l*96 + j] = a0; G[l*96 + SSN + j] = a1; G[l*96 + 2*SSN + j] = a2;
}

// ---------------- readout: thread per (path, hop), streaming low-VGPR form ----
__global__ __launch_bounds__(256, 4) void k_readout(
    const float* __restrict__ seq, const int* __restrict__ l2p,
    const float* __restrict__ cap, const float* __restrict__ ft,
    const float* __restrict__ fpk,
    const float* __restrict__ w1, const float* __restrict__ b1,
    const float* __restrict__ w2, const float* __restrict__ b2,
    const float* __restrict__ w3, const float* __restrict__ b3,
    float* __restrict__ out)
{
    int g = blockIdx.x*256 + threadIdx.x;
    int p = g >> 3, t = g & 7;
    if (p >= PN) p = PN-1;               // tail: duplicate same-value writes, benign
    int lk = l2p[p*HN + t];
    const float4* s4 = (const float4*)(seq + (p*HN+t)*SSN);
    float h1[16];
    #pragma unroll
    for (int j=0;j<16;j++) h1[j] = b1[j];
    #pragma unroll
    for (int q=0;q<8;q++){
        float4 v = s4[q];
        #pragma unroll
        for (int j=0;j<16;j++){
            h1[j] += v.x*w1[(4*q+0)*16+j] + v.y*w1[(4*q+1)*16+j]
                   + v.z*w1[(4*q+2)*16+j] + v.w*w1[(4*q+3)*16+j];
        }
    }
    #pragma unroll
    for (int j=0;j<16;j++) h1[j] = fmaxf(h1[j], 0.f);
    float h2[16];
    #pragma unroll
    for (int j=0;j<16;j++) h2[j] = b2[j];
    #pragma unroll
    for (int k=0;k<16;k++){
        float hk = h1[k];
        #pragma unroll
        for (int j=0;j<16;j++) h2[j] += hk*w2[k*16+j];
    }
    float occ = b3[0];
    #pragma unroll
    for (int k=0;k<16;k++) occ += fmaxf(h2[k], 0.f)*w3[k];
    float icg = rcp_(cap[lk]) * 1e-9f;
    float qd  = occ * icg;
    float inv = icg;
    qd  += __shfl_xor(qd, 1);  inv += __shfl_xor(inv, 1);
    qd  += __shfl_xor(qd, 2);  inv += __shfl_xor(inv, 2);
    qd  += __shfl_xor(qd, 4);  inv += __shfl_xor(inv, 4);
    if ((threadIdx.x & 7) == 0)
        out[p] = qd + ft[p]*rcp_(fpk[p])*inv;
}

extern "C" void kernel_launch(void* const* d_in, const int* in_sizes, int n_in,
                              void* d_out, int out_size, void* d_ws, size_t ws_size,
                              hipStream_t stream)
{
    (void)in_sizes; (void)n_in; (void)out_size; (void)ws_size;
    const float* ft    = (const float*)d_in[0];
    const float* fpk   = (const float*)d_in[1];
    const float* flam  = (const float*)d_in[2];
    const float* fob   = (const float*)d_in[3];
    const float* fon   = (const float*)d_in[4];
    const float* foff  = (const float*)d_in[5];
    const float* cap   = (const float*)d_in[6];
    const float* pe_w1 = (const float*)d_in[7];
    const float* pe_b1 = (const float*)d_in[8];
    const float* pe_w2 = (const float*)d_in[9];
    const float* pe_b2 = (const float*)d_in[10];
    const float* le_w1 = (const float*)d_in[11];
    const float* le_b1 = (const float*)d_in[12];
    const float* le_w2 = (const float*)d_in[13];
    const float* le_b2 = (const float*)d_in[14];
    const float* qe_w1 = (const float*)d_in[15];
    const float* qe_b1 = (const float*)d_in[16];
    const float* qe_w2 = (const float*)d_in[17];
    const float* qe_b2 = (const float*)d_in[18];
    const float* pWx   = (const float*)d_in[19];
    const float* pWh   = (const float*)d_in[20];
    const float* pbi   = (const float*)d_in[21];
    const float* pbh   = (const float*)d_in[22];
    const float* qWx   = (const float*)d_in[23];
    const float* qWh   = (const float*)d_in[24];
    const float* qbi   = (const float*)d_in[25];
    const float* qbh   = (const float*)d_in[26];
    const float* lWx   = (const float*)d_in[27];
    const float* lWh   = (const float*)d_in[28];
    const float* lbi   = (const float*)d_in[29];
    const float* lbh   = (const float*)d_in[30];
    const float* ro_w1 = (const float*)d_in[31];
    const float* ro_b1 = (const float*)d_in[32];
    const float* ro_w2 = (const float*)d_in[33];
    const float* ro_b2 = (const float*)d_in[34];
    const float* ro_w3 = (const float*)d_in[35];
    const float* ro_b3 = (const float*)d_in[36];
    const int* fdist = (const int*)d_in[37];
    const int* btype = (const int*)d_in[38];
    const int* l2p   = (const int*)d_in[39];
    const int* p2l   = (const int*)d_in[40];
    const int* q2l   = (const int*)d_in[41];

    float* ws = (float*)d_ws;
    float* pWhp = ws + OFF_PWHP;
    float* pWxp = ws + OFF_PWXP;
    float* qWxp = ws + OFF_QWXP;
    float* qWhp = ws + OFF_QWHP;
    float* lWxp = ws + OFF_LWXP;
    float* lWhp = ws + OFF_LWHP;
    float* path_state  = ws + OFF_PATH;
    float* seq         = ws + OFF_SEQ;
    float* queue_state = ws + OFF_QST;
    float* link_state  = ws + OFF_LST;
    float* G           = ws + OFF_G;

    k_pack<<<108, 256, 0, stream>>>(pWh, pWx, qWx, qWh, lWx, lWh, ws);
    k_path_init<<<(PN+255)/256, 256, 0, stream>>>(ft, fpk, flam, fob, fon, foff, fdist,
                                                  pe_w1, pe_b1, pe_w2, pe_b2, path_state);
    k_link_init<<<(LN+63)/64, 64, 0, stream>>>(ft, cap, p2l, btype,
                                               le_w1, le_b1, le_w2, le_b2,
                                               qe_w1, qe_b1, qe_w2, qe_b2,
                                               pWxp, pbi, link_state, queue_state, G);
    for (int it = 0; it < 8; ++it){
        k_path_gru<<<PN/4, 256, 0, stream>>>(G, l2p, pWhp, pbh, path_state, seq);
        k_queue_gru<<<LN/4, 256, 0, stream>>>(seq, p2l, qWxp, qWhp, qbi, qbh, queue_state);
        k_link_gru<<<LN/4, 256, 0, stream>>>(queue_state, q2l, lWxp, lWhp, lbi, lbh,
                                             pWxp, pbi, link_state, G);
    }
    k_readout<<<(PN*HN+255)/256, 256, 0, stream>>>(seq, l2p, cap, ft, fpk,
                                                   ro_w1, ro_b1, ro_w2, ro_b2, ro_w3, ro_b3,
                                                   (float*)d_out);
}